// Round 4
// baseline (27.736 us; speedup 1.0000x reference)
//
#include <hip/hip_runtime.h>

// Exponential concordance loss — single kernel (last-block-done finalize):
// loss_sum = sum over (a,b) with dur[b] < dur[a] and ev[b]==1 of exp(p[a]-p[b])
//          = sum_a epos[a] * sum_{b: dur_b<dur_a} w[b],  w[b]=ev[b]?exp(-p[b]):0
// out = loss_sum / num_pairs
//
// Block = (colGroup of TPB*NB columns) x (aChunk of ACHUNK rows). Rows staged
// in LDS as (dur, exp(p)); columns in registers as (dur_b, w_b). Block partials
// go to d_ws; the last block to finish (agent-scope ticket) reduces them in a
// fixed order -> deterministic output. Cross-XCD visibility via __hip_atomic_*
// agent-scope stores/loads (per-XCD L2 is not coherent).

#define TPB 256
#define NB 8          // columns per thread (register-resident)
#define ACHUNK 64     // rows staged in LDS per block

__global__ void __launch_bounds__(TPB) pair_single(const float* __restrict__ preds,
                                                   const float2* __restrict__ targets, // (dur, ev)
                                                   float* __restrict__ psum,
                                                   int* __restrict__ pcnt,
                                                   int* __restrict__ ticket,
                                                   float* __restrict__ out,
                                                   int n, int nblocks) {
    const int colGroups = n / (TPB * NB);          // 8192/2048 = 4
    const int cg = blockIdx.x % colGroups;
    const int ac = blockIdx.x / colGroups;
    const int base_a = ac * ACHUNK;
    const int base_b = cg * TPB * NB + threadIdx.x;

    __shared__ float2 sa[ACHUNK];                  // (dur_a, epos_a)
    if (threadIdx.x < ACHUNK) {
        int a = base_a + threadIdx.x;
        float2 t = targets[a];
        sa[threadIdx.x] = make_float2(t.x, __expf(preds[a]));
    }

    float db[NB], wb[NB];
#pragma unroll
    for (int k = 0; k < NB; ++k) {
        int b = base_b + k * TPB;                  // coalesced
        float2 t = targets[b];
        float  p = preds[b];
        db[k] = t.x;
        wb[k] = (t.y == 1.0f) ? __expf(-p) : 0.0f;
    }
    __syncthreads();

    float sum[NB];
    int   cnt[NB];
#pragma unroll
    for (int k = 0; k < NB; ++k) { sum[k] = 0.0f; cnt[k] = 0; }

#pragma unroll 8
    for (int i = 0; i < ACHUNK; ++i) {
        float2 a = sa[i];                          // uniform address -> broadcast
#pragma unroll
        for (int k = 0; k < NB; ++k) {
            bool v = db[k] < a.x;
            sum[k] += v ? a.y : 0.0f;
            cnt[k] += v;
        }
    }

    float lsum = 0.0f;
    int   lcnt = 0;
#pragma unroll
    for (int k = 0; k < NB; ++k) {
        if (wb[k] > 0.0f) {                        // ev[b]==1  <=>  w_b>0
            lsum += wb[k] * sum[k];
            lcnt += cnt[k];
        }
    }

    // ---- block reduction of (lsum, lcnt) ----
    __shared__ float ssum[TPB];
    __shared__ int   scnt[TPB];
    ssum[threadIdx.x] = lsum;
    scnt[threadIdx.x] = lcnt;
    __syncthreads();
    for (int s = TPB / 2; s > 0; s >>= 1) {
        if (threadIdx.x < s) {
            ssum[threadIdx.x] += ssum[threadIdx.x + s];
            scnt[threadIdx.x] += scnt[threadIdx.x + s];
        }
        __syncthreads();
    }

    // ---- publish partials, grab ticket ----
    __shared__ int isLast;
    if (threadIdx.x == 0) {
        __hip_atomic_store(&psum[blockIdx.x], ssum[0], __ATOMIC_RELAXED, __HIP_MEMORY_SCOPE_AGENT);
        __hip_atomic_store(&pcnt[blockIdx.x], scnt[0], __ATOMIC_RELAXED, __HIP_MEMORY_SCOPE_AGENT);
        int t = __hip_atomic_fetch_add(ticket, 1, __ATOMIC_ACQ_REL, __HIP_MEMORY_SCOPE_AGENT);
        isLast = (t == nblocks - 1);
    }
    __syncthreads();
    if (!isLast) return;

    // ---- last block: reduce all partials in fixed order ----
    __shared__ double    ds[TPB];
    __shared__ long long dc[TPB];
    double    ls = 0.0;
    long long lc = 0;
    for (int i = threadIdx.x; i < nblocks; i += TPB) {
        float f = __hip_atomic_load(&psum[i], __ATOMIC_RELAXED, __HIP_MEMORY_SCOPE_AGENT);
        int   c = __hip_atomic_load(&pcnt[i], __ATOMIC_RELAXED, __HIP_MEMORY_SCOPE_AGENT);
        ls += (double)f;
        lc += (long long)c;
    }
    ds[threadIdx.x] = ls;
    dc[threadIdx.x] = lc;
    __syncthreads();
    for (int s = TPB / 2; s > 0; s >>= 1) {
        if (threadIdx.x < s) {
            ds[threadIdx.x] += ds[threadIdx.x + s];
            dc[threadIdx.x] += dc[threadIdx.x + s];
        }
        __syncthreads();
    }
    if (threadIdx.x == 0) {
        out[0] = (dc[0] > 0) ? (float)(ds[0] / (double)dc[0]) : 0.0f;
    }
}

extern "C" void kernel_launch(void* const* d_in, const int* in_sizes, int n_in,
                              void* d_out, int out_size, void* d_ws, size_t ws_size,
                              hipStream_t stream) {
    const float*  preds   = (const float*)d_in[0];
    const float2* targets = (const float2*)d_in[1];   // [n] of (dur, ev)
    float* out = (float*)d_out;
    int n = in_sizes[0];   // 8192

    int colGroups = n / (TPB * NB);                // 4
    int aChunks   = n / ACHUNK;                    // 128
    int nblocks   = colGroups * aChunks;           // 512

    // ws layout: psum[nblocks] f32, pcnt[nblocks] i32, ticket i32
    float* psum   = (float*)d_ws;
    int*   pcnt   = (int*)(psum + nblocks);
    int*   ticket = pcnt + nblocks;

    hipMemsetAsync(ticket, 0, sizeof(int), stream);
    pair_single<<<nblocks, TPB, 0, stream>>>(preds, targets, psum, pcnt, ticket, out, n, nblocks);
}

// Round 5
// 23.434 us; speedup vs baseline: 1.1836x; 1.1836x over previous
//
#include <hip/hip_runtime.h>

// Exponential concordance loss — single kernel, zero extra dispatches:
// loss_sum = sum over (a,b) with dur[b] < dur[a] and ev[b]==1 of exp(p[a]-p[b])
//          = sum_a epos[a] * sum_{b: dur_b<dur_a} w[b],  w[b]=ev[b]?exp(-p[b]):0
// out = loss_sum / num_pairs
//
// Block = (colGroup of TPB*NB columns) x (aChunk of ACHUNK rows). Rows staged
// in LDS as (dur, exp(p)); columns in registers as (dur_b, w_b). Block partials
// -> d_ws; last-arriving block (module-global ticket, agent scope) reduces them
// in fixed order (deterministic) and RESETS the ticket to 0 for the next call.
// g_ticket lives in module .data (load-time init 0), not in d_ws, so the
// harness's 0xAA workspace poison never corrupts it and no memset is needed.

#define TPB 256
#define NB 8          // columns per thread (register-resident)
#define ACHUNK 64     // rows staged in LDS per block

__device__ int g_ticket = 0;

__global__ void __launch_bounds__(TPB) pair_single(const float* __restrict__ preds,
                                                   const float2* __restrict__ targets, // (dur, ev)
                                                   float* __restrict__ psum,
                                                   int* __restrict__ pcnt,
                                                   float* __restrict__ out,
                                                   int n, int nblocks) {
    const int colGroups = n / (TPB * NB);          // 8192/2048 = 4
    const int cg = blockIdx.x % colGroups;
    const int ac = blockIdx.x / colGroups;
    const int base_a = ac * ACHUNK;
    const int base_b = cg * TPB * NB + threadIdx.x;

    __shared__ float2 sa[ACHUNK];                  // (dur_a, epos_a)
    if (threadIdx.x < ACHUNK) {
        int a = base_a + threadIdx.x;
        float2 t = targets[a];
        sa[threadIdx.x] = make_float2(t.x, __expf(preds[a]));
    }

    float db[NB], wb[NB];
#pragma unroll
    for (int k = 0; k < NB; ++k) {
        int b = base_b + k * TPB;                  // coalesced
        float2 t = targets[b];
        float  p = preds[b];
        db[k] = t.x;
        wb[k] = (t.y == 1.0f) ? __expf(-p) : 0.0f;
    }
    __syncthreads();

    float sum[NB];
    int   cnt[NB];
#pragma unroll
    for (int k = 0; k < NB; ++k) { sum[k] = 0.0f; cnt[k] = 0; }

#pragma unroll 8
    for (int i = 0; i < ACHUNK; ++i) {
        float2 a = sa[i];                          // uniform address -> broadcast
#pragma unroll
        for (int k = 0; k < NB; ++k) {
            bool v = db[k] < a.x;
            sum[k] += v ? a.y : 0.0f;
            cnt[k] += v;
        }
    }

    float lsum = 0.0f;
    int   lcnt = 0;
#pragma unroll
    for (int k = 0; k < NB; ++k) {
        if (wb[k] > 0.0f) {                        // ev[b]==1  <=>  w_b>0
            lsum += wb[k] * sum[k];
            lcnt += cnt[k];
        }
    }

    // ---- block reduction of (lsum, lcnt) ----
    __shared__ float ssum[TPB];
    __shared__ int   scnt[TPB];
    ssum[threadIdx.x] = lsum;
    scnt[threadIdx.x] = lcnt;
    __syncthreads();
    for (int s = TPB / 2; s > 0; s >>= 1) {
        if (threadIdx.x < s) {
            ssum[threadIdx.x] += ssum[threadIdx.x + s];
            scnt[threadIdx.x] += scnt[threadIdx.x + s];
        }
        __syncthreads();
    }

    // ---- publish partials, grab ticket ----
    __shared__ int isLast;
    if (threadIdx.x == 0) {
        __hip_atomic_store(&psum[blockIdx.x], ssum[0], __ATOMIC_RELAXED, __HIP_MEMORY_SCOPE_AGENT);
        __hip_atomic_store(&pcnt[blockIdx.x], scnt[0], __ATOMIC_RELAXED, __HIP_MEMORY_SCOPE_AGENT);
        int t = __hip_atomic_fetch_add(&g_ticket, 1, __ATOMIC_ACQ_REL, __HIP_MEMORY_SCOPE_AGENT);
        isLast = (t == nblocks - 1);
    }
    __syncthreads();
    if (!isLast) return;

    // ---- last block: reduce all partials in fixed order ----
    __shared__ double    ds[TPB];
    __shared__ long long dc[TPB];
    double    ls = 0.0;
    long long lc = 0;
    for (int i = threadIdx.x; i < nblocks; i += TPB) {
        float f = __hip_atomic_load(&psum[i], __ATOMIC_RELAXED, __HIP_MEMORY_SCOPE_AGENT);
        int   c = __hip_atomic_load(&pcnt[i], __ATOMIC_RELAXED, __HIP_MEMORY_SCOPE_AGENT);
        ls += (double)f;
        lc += (long long)c;
    }
    ds[threadIdx.x] = ls;
    dc[threadIdx.x] = lc;
    __syncthreads();
    for (int s = TPB / 2; s > 0; s >>= 1) {
        if (threadIdx.x < s) {
            ds[threadIdx.x] += ds[threadIdx.x + s];
            dc[threadIdx.x] += dc[threadIdx.x + s];
        }
        __syncthreads();
    }
    if (threadIdx.x == 0) {
        out[0] = (dc[0] > 0) ? (float)(ds[0] / (double)dc[0]) : 0.0f;
        // reset ticket for the next call (all blocks of this call have arrived)
        __hip_atomic_store(&g_ticket, 0, __ATOMIC_RELAXED, __HIP_MEMORY_SCOPE_AGENT);
    }
}

extern "C" void kernel_launch(void* const* d_in, const int* in_sizes, int n_in,
                              void* d_out, int out_size, void* d_ws, size_t ws_size,
                              hipStream_t stream) {
    const float*  preds   = (const float*)d_in[0];
    const float2* targets = (const float2*)d_in[1];   // [n] of (dur, ev)
    float* out = (float*)d_out;
    int n = in_sizes[0];   // 8192

    int colGroups = n / (TPB * NB);                // 4
    int aChunks   = n / ACHUNK;                    // 128
    int nblocks   = colGroups * aChunks;           // 512

    // ws layout: psum[nblocks] f32, pcnt[nblocks] i32
    float* psum = (float*)d_ws;
    int*   pcnt = (int*)(psum + nblocks);

    pair_single<<<nblocks, TPB, 0, stream>>>(preds, targets, psum, pcnt, out, n, nblocks);
}

// Round 6
// 20.249 us; speedup vs baseline: 1.3698x; 1.1573x over previous
//
#include <hip/hip_runtime.h>

// Exponential concordance loss — single kernel, cache-op-free last-block sync:
// loss_sum = sum over (a,b) with dur[b] < dur[a] and ev[b]==1 of exp(p[a]-p[b])
//          = sum_a epos[a] * sum_{b: dur_b<dur_a} w[b],  w[b]=ev[b]?exp(-p[b]):0
// out = loss_sum / num_pairs
//
// Sync design: each block publishes (sum,cnt) packed in ONE 8-byte relaxed
// agent-scope atomic store (write-through sc0/sc1 -> coherence point, no L2
// writeback), drains vmcnt(0), then relaxed agent fetch_add on a module-global
// ticket. Exactly one block sees t==nblocks-1; it reads all partials with
// relaxed agent atomic loads (cache-bypassing) in fixed order -> deterministic.
// No ACQ_REL -> no per-block buffer_wbl2/buffer_inv (that was R5's ~12us).

#define TPB 256
#define NB 8          // columns per thread (register-resident)
#define ACHUNK 64     // rows staged in LDS per block

__device__ int g_ticket = 0;

union PackSC {
    struct { float s; int c; } sc;
    unsigned long long u;
};

__global__ void __launch_bounds__(TPB) pair_single(const float* __restrict__ preds,
                                                   const float2* __restrict__ targets, // (dur, ev)
                                                   unsigned long long* __restrict__ partials,
                                                   float* __restrict__ out,
                                                   int n, int nblocks) {
    const int colGroups = n / (TPB * NB);          // 8192/2048 = 4
    const int cg = blockIdx.x % colGroups;
    const int ac = blockIdx.x / colGroups;
    const int base_a = ac * ACHUNK;
    const int base_b = cg * TPB * NB + threadIdx.x;

    __shared__ float2 sa[ACHUNK];                  // (dur_a, epos_a)
    if (threadIdx.x < ACHUNK) {
        int a = base_a + threadIdx.x;
        float2 t = targets[a];
        sa[threadIdx.x] = make_float2(t.x, __expf(preds[a]));
    }

    float db[NB], wb[NB];
#pragma unroll
    for (int k = 0; k < NB; ++k) {
        int b = base_b + k * TPB;                  // coalesced
        float2 t = targets[b];
        float  p = preds[b];
        db[k] = t.x;
        wb[k] = (t.y == 1.0f) ? __expf(-p) : 0.0f;
    }
    __syncthreads();

    float sum[NB];
    int   cnt[NB];
#pragma unroll
    for (int k = 0; k < NB; ++k) { sum[k] = 0.0f; cnt[k] = 0; }

#pragma unroll 8
    for (int i = 0; i < ACHUNK; ++i) {
        float2 a = sa[i];                          // uniform address -> broadcast
#pragma unroll
        for (int k = 0; k < NB; ++k) {
            bool v = db[k] < a.x;
            sum[k] += v ? a.y : 0.0f;
            cnt[k] += v;
        }
    }

    float lsum = 0.0f;
    int   lcnt = 0;
#pragma unroll
    for (int k = 0; k < NB; ++k) {
        if (wb[k] > 0.0f) {                        // ev[b]==1  <=>  w_b>0
            lsum += wb[k] * sum[k];
            lcnt += cnt[k];
        }
    }

    // ---- block reduction of (lsum, lcnt) ----
    __shared__ float ssum[TPB];
    __shared__ int   scnt[TPB];
    ssum[threadIdx.x] = lsum;
    scnt[threadIdx.x] = lcnt;
    __syncthreads();
    for (int s = TPB / 2; s > 0; s >>= 1) {
        if (threadIdx.x < s) {
            ssum[threadIdx.x] += ssum[threadIdx.x + s];
            scnt[threadIdx.x] += scnt[threadIdx.x + s];
        }
        __syncthreads();
    }

    // ---- publish packed partial (write-through), drain, relaxed ticket ----
    __shared__ int isLast;
    if (threadIdx.x == 0) {
        PackSC pk;
        pk.sc.s = ssum[0];
        pk.sc.c = scnt[0];
        __hip_atomic_store(&partials[blockIdx.x], pk.u,
                           __ATOMIC_RELAXED, __HIP_MEMORY_SCOPE_AGENT);
        asm volatile("s_waitcnt vmcnt(0)" ::: "memory");  // store ack'd at coherence point
        int t = __hip_atomic_fetch_add(&g_ticket, 1,
                                       __ATOMIC_RELAXED, __HIP_MEMORY_SCOPE_AGENT);
        isLast = (t == nblocks - 1);
    }
    __syncthreads();
    if (!isLast) return;

    // ---- last block: reduce all partials in fixed order ----
    __shared__ double    ds[TPB];
    __shared__ long long dc[TPB];
    double    ls = 0.0;
    long long lc = 0;
    for (int i = threadIdx.x; i < nblocks; i += TPB) {
        PackSC pk;
        pk.u = __hip_atomic_load(&partials[i], __ATOMIC_RELAXED, __HIP_MEMORY_SCOPE_AGENT);
        ls += (double)pk.sc.s;
        lc += (long long)pk.sc.c;
    }
    ds[threadIdx.x] = ls;
    dc[threadIdx.x] = lc;
    __syncthreads();
    for (int s = TPB / 2; s > 0; s >>= 1) {
        if (threadIdx.x < s) {
            ds[threadIdx.x] += ds[threadIdx.x + s];
            dc[threadIdx.x] += dc[threadIdx.x + s];
        }
        __syncthreads();
    }
    if (threadIdx.x == 0) {
        out[0] = (dc[0] > 0) ? (float)(ds[0] / (double)dc[0]) : 0.0f;
        // reset ticket for the next call (all blocks of this call have arrived)
        __hip_atomic_store(&g_ticket, 0, __ATOMIC_RELAXED, __HIP_MEMORY_SCOPE_AGENT);
    }
}

extern "C" void kernel_launch(void* const* d_in, const int* in_sizes, int n_in,
                              void* d_out, int out_size, void* d_ws, size_t ws_size,
                              hipStream_t stream) {
    const float*  preds   = (const float*)d_in[0];
    const float2* targets = (const float2*)d_in[1];   // [n] of (dur, ev)
    float* out = (float*)d_out;
    int n = in_sizes[0];   // 8192

    int colGroups = n / (TPB * NB);                // 4
    int aChunks   = n / ACHUNK;                    // 128
    int nblocks   = colGroups * aChunks;           // 512

    // ws layout: partials[nblocks] packed (float,int)
    unsigned long long* partials = (unsigned long long*)d_ws;

    pair_single<<<nblocks, TPB, 0, stream>>>(preds, targets, partials, out, n, nblocks);
}